// Round 5
// baseline (151.547 us; speedup 1.0000x reference)
//
#include <hip/hip_runtime.h>
#include <hip/hip_bf16.h>

#define VDIM 50257
#define EDIM 128
#define MROWS 2048
#define KMAIN 50240            // 1570 k-steps of 32; tail of 17 in fp32 in k_reduce
#define KTAIL 17               // VDIM - KMAIN
#define KSTEPS 1570
#define SPLIT 8
#define BM 32
#define PITCH 520              // shorts per LDS row (1040 B): 16B-aligned, conflict-free
#define LB (BM * PITCH * 2)    // bytes per LDS buffer = 33280

using short8_t = __attribute__((ext_vector_type(8))) short;
using float4_t = __attribute__((ext_vector_type(4))) float;

static __device__ __forceinline__ short f2bf(float f) {
    union { __hip_bfloat16 h; short s; } u;
    u.h = __float2bfloat16(f);
    return u.s;
}

static __device__ __forceinline__ unsigned pack_bf2(float lo, float hi) {
    unsigned l = (unsigned short)f2bf(lo);
    unsigned h = (unsigned short)f2bf(hi);
    return l | (h << 16);
}

// W (VDIM x EDIM fp32) -> Wt2[step][128 e][32 k] bf16 (each 8 KB B-tile contiguous).
__global__ __launch_bounds__(256) void k_wt2(const float* __restrict__ W,
                                             short* __restrict__ Wt2) {
    __shared__ float tile[32][132];             // +4 pad for column reads
    const int t = threadIdx.x;
    const int step = blockIdx.x;                // 0..1569
    const float* src = W + (size_t)step * 4096; // 32 k-rows x 128 e, contiguous
    #pragma unroll
    for (int p = 0; p < 16; ++p) {
        int idx = p * 256 + t;
        tile[idx >> 7][idx & 127] = src[idx];
    }
    __syncthreads();
    const int e = t >> 1, half = t & 1;
    short* dst = Wt2 + (size_t)step * 4096 + e * 32 + half * 16;
    #pragma unroll
    for (int q = 0; q < 2; ++q) {
        short8_t pk;
        #pragma unroll
        for (int i = 0; i < 8; ++i) pk[i] = f2bf(tile[half * 16 + q * 8 + i][e]);
        *reinterpret_cast<short8_t*>(dst + q * 8) = pk;
    }
}

// Split-K bf16 MFMA GEMM. BK=512 superstep: 2 KB contiguous per row-visit
// (DRAM page amortization — the R1->R3 lever, pushed 4x further).
// Grid 512 = 64 mt x 8 s, 2 blocks/CU; s=bid&7 pins splits to XCDs (Wt2 chunk
// 1.6 MB L2-resident). Per wave: 32 rows x 32 cols, zero redundant B loads.
__global__ __launch_bounds__(256, 2) void k_main(const float* __restrict__ A,
                                                 const short* __restrict__ Wt2,
                                                 float* __restrict__ P) {
    __shared__ short tile[2][BM][PITCH];        // 66560 B total, double-buffered

    const int bid = blockIdx.x;
    const int s   = bid & 7;
    const int mt  = bid >> 3;                   // 0..63
    const int t = threadIdx.x, w = t >> 6, l = t & 63;

    const int start  = (s * KSTEPS) / SPLIT;
    const int end    = ((s + 1) * KSTEPS) / SPLIT;
    const int nsteps = end - start;             // 196 or 197 k-steps of 32
    const int NSS    = (nsteps + 15) / 16;      // supersteps of 16 k-steps (BK=512)
    const size_t kb  = (size_t)start * 32;

    // staging: thread covers row t>>3, dword base (t&7)*4, i=0..15 at +i*32 dwords.
    // per instr: 8 lanes x 16B = 128 B contiguous per row; 16 instrs span 2 KB/row.
    const int srow = t >> 3;
    const int sdw  = (t & 7) * 4;
    const float* aptr = A + (size_t)(mt * BM + srow) * VDIM + kb + sdw;

    // fragment ids: wave w owns col-fragments {2w, 2w+1}
    const int rl = l & 15, kg = l >> 4;
    const int cf0 = 2 * w;

    char* const lds = (char*)&tile[0][0][0];
    const int fr0 = rl * (PITCH * 2) + kg * 16;         // rowfrag 0 byte offset
    const int fr1 = fr0 + 16 * (PITCH * 2);             // rowfrag 1
    const int swo = srow * (PITCH * 2) + sdw * 2;       // stage write byte offset

    float4_t acc[2][2];
    #pragma unroll
    for (int i = 0; i < 2; ++i)
        #pragma unroll
        for (int j = 0; j < 2; ++j) acc[i][j] = (float4_t){0.f, 0.f, 0.f, 0.f};

    float4_t fs[16];                            // in-flight superstep (64 VGPR, T14)

    auto load_stage = [&](int ssn, int nj) {
        const float* p = aptr + (size_t)ssn * 512;
        #pragma unroll
        for (int i = 0; i < 16; ++i)
            if (i < nj) __builtin_memcpy(&fs[i], p + i * 32, 16);  // rows 4B-aligned
    };
    auto write_stage = [&](int buf, int nj) {
        #pragma unroll
        for (int i = 0; i < 16; ++i)
            if (i < nj) {
                uint2 v;
                v.x = pack_bf2(fs[i][0], fs[i][1]);
                v.y = pack_bf2(fs[i][2], fs[i][3]);
                *reinterpret_cast<uint2*>(lds + buf * LB + swo + i * 64) = v;
            }
    };
    auto compute_step = [&](int buf, int gstep, int j) {
        const short* bb = Wt2 + (size_t)gstep * 4096 + (size_t)(cf0 * 16 + rl) * 32 + kg * 8;
        short8_t b0 = *reinterpret_cast<const short8_t*>(bb);
        short8_t b1 = *reinterpret_cast<const short8_t*>(bb + 16 * 32);
        short8_t a0 = *reinterpret_cast<const short8_t*>(lds + buf * LB + fr0 + j * 64);
        short8_t a1 = *reinterpret_cast<const short8_t*>(lds + buf * LB + fr1 + j * 64);
        acc[0][0] = __builtin_amdgcn_mfma_f32_16x16x32_bf16(a0, b0, acc[0][0], 0, 0, 0);
        acc[0][1] = __builtin_amdgcn_mfma_f32_16x16x32_bf16(a0, b1, acc[0][1], 0, 0, 0);
        acc[1][0] = __builtin_amdgcn_mfma_f32_16x16x32_bf16(a1, b0, acc[1][0], 0, 0, 0);
        acc[1][1] = __builtin_amdgcn_mfma_f32_16x16x32_bf16(a1, b1, acc[1][1], 0, 0, 0);
    };

    // prologue: stage superstep 0 into buf 0 (nsteps >= 196, so full 16)
    load_stage(0, 16);
    write_stage(0, 16);
    __syncthreads();

    for (int ss = 0; ss < NSS; ++ss) {
        const int buf  = ss & 1;
        const int rem  = nsteps - ss * 16;
        const int curn = rem < 16 ? rem : 16;
        const int nrem = nsteps - (ss + 1) * 16;
        const int nxtn = (ss + 1 < NSS) ? (nrem < 16 ? nrem : 16) : 0;
        load_stage(ss + 1, nxtn);               // issue early; MFMA hides HBM latency
        const int g0 = start + ss * 16;
        #pragma unroll
        for (int j = 0; j < 16; ++j)
            if (j < curn) compute_step(buf, g0 + j, j);
        write_stage(buf ^ 1, nxtn);             // vmcnt waits land here
        __syncthreads();
    }

    // Partial write: C/D layout col = lane&15, row = (lane>>4)*4 + j  [m89-verified]
    float* pout = P + ((size_t)s * MROWS + (size_t)mt * BM) * EDIM + cf0 * 16;
    #pragma unroll
    for (int rf = 0; rf < 2; ++rf)
        #pragma unroll
        for (int cf = 0; cf < 2; ++cf)
            #pragma unroll
            for (int j = 0; j < 4; ++j) {
                int rr = rf * 16 + kg * 4 + j;
                int cc = cf * 16 + rl;
                pout[(size_t)rr * EDIM + cc] = acc[rf][cf][j];
            }
}

// out = bias + sum of SPLIT partials + fp32 K-tail, float4-vectorized.
__global__ __launch_bounds__(256) void k_reduce(const float* __restrict__ P,
                                                const float* __restrict__ A,
                                                const float* __restrict__ W,
                                                const float* __restrict__ bias,
                                                float* __restrict__ out) {
    const int i4 = blockIdx.x * 256 + threadIdx.x;   // float4 index, 65536 total
    const int m  = i4 >> 5;                          // 32 float4 per output row
    const int e4 = i4 & 31;
    float4_t acc = reinterpret_cast<const float4_t*>(bias)[e4];
    #pragma unroll
    for (int j = 0; j < KTAIL; ++j) {
        float a = A[(size_t)m * VDIM + KMAIN + j];
        float4_t w = reinterpret_cast<const float4_t*>(W + (size_t)(KMAIN + j) * EDIM)[e4];
        acc += a * w;
    }
    float4_t ps = {0.f, 0.f, 0.f, 0.f};
    #pragma unroll
    for (int p = 0; p < SPLIT; ++p)
        ps += reinterpret_cast<const float4_t*>(P)[(size_t)p * (MROWS * EDIM / 4) + i4];
    acc += ps;
    reinterpret_cast<float4_t*>(out)[i4] = acc;
}

// Emergency fallback if workspace is too small: plain fp32, deterministic.
__global__ __launch_bounds__(256) void k_naive(const float* __restrict__ A,
                                               const float* __restrict__ W,
                                               const float* __restrict__ bias,
                                               float* __restrict__ out) {
    const int e  = threadIdx.x & 127;
    const int mi = threadIdx.x >> 7;
    const int m0 = blockIdx.x * 8 + mi;
    float acc[4] = {0.f, 0.f, 0.f, 0.f};
    for (int k = 0; k < VDIM; ++k) {
        float w = W[(size_t)k * EDIM + e];
        #pragma unroll
        for (int q = 0; q < 4; ++q)
            acc[q] += A[(size_t)(m0 + q * 2) * VDIM + k] * w;
    }
    #pragma unroll
    for (int q = 0; q < 4; ++q)
        out[(size_t)(m0 + q * 2) * EDIM + e] = acc[q] + bias[e];
}

extern "C" void kernel_launch(void* const* d_in, const int* in_sizes, int n_in,
                              void* d_out, int out_size, void* d_ws, size_t ws_size,
                              hipStream_t stream) {
    const float* A    = (const float*)d_in[0];  // (16,128,50257) fp32
    const float* W    = (const float*)d_in[1];  // (50257,128) fp32
    const float* bias = (const float*)d_in[2];  // (128,) fp32
    float* out = (float*)d_out;                 // (16,128,128) fp32

    const size_t WT2_BYTES = (size_t)KSTEPS * 4096 * sizeof(short);         // 12.86 MB
    const size_t P_BYTES   = (size_t)SPLIT * MROWS * EDIM * sizeof(float);  // 8.39 MB

    if (ws_size >= WT2_BYTES + P_BYTES) {
        short* Wt2 = (short*)d_ws;
        float* P   = (float*)((char*)d_ws + WT2_BYTES);
        k_wt2<<<KSTEPS, 256, 0, stream>>>(W, Wt2);
        k_main<<<(MROWS / BM) * SPLIT, 256, 0, stream>>>(A, Wt2, P);
        k_reduce<<<(MROWS * EDIM) / (256 * 4), 256, 0, stream>>>(P, A, W, bias, out);
    } else {
        k_naive<<<MROWS / 8, 256, 0, stream>>>(A, W, bias, out);
    }
}

// Round 6
// 126.843 us; speedup vs baseline: 1.1948x; 1.1948x over previous
//
#include <hip/hip_runtime.h>
#include <hip/hip_bf16.h>

#define VDIM 50257
#define EDIM 128
#define MROWS 2048
#define KMAIN 50240            // 1570 k-steps of 32; tail of 17 in fp32 in k_reduce
#define KTAIL 17               // VDIM - KMAIN
#define KSTEPS 1570
#define SPLIT 16
#define BM 32
#define BKS 8                  // k-steps per superstep (BK = 256)
#define PITCH 264              // shorts per LDS row (528 B): uniform bank quads
#define LBYTES (BM * PITCH * 2)   // 16896 B per buffer

using short8_t = __attribute__((ext_vector_type(8))) short;
using float4_t = __attribute__((ext_vector_type(4))) float;

static __device__ __forceinline__ short f2bf(float f) {
    union { __hip_bfloat16 h; short s; } u;
    u.h = __float2bfloat16(f);
    return u.s;
}

static __device__ __forceinline__ unsigned pack_bf2(float lo, float hi) {
    unsigned l = (unsigned short)f2bf(lo);
    unsigned h = (unsigned short)f2bf(hi);
    return l | (h << 16);
}

// W (VDIM x EDIM fp32) -> Wt2[step][128 e][32 k] bf16 (each 8 KB B-tile contiguous).
__global__ __launch_bounds__(256) void k_wt2(const float* __restrict__ W,
                                             short* __restrict__ Wt2) {
    __shared__ float tile[32][132];             // +4 pad for column reads
    const int t = threadIdx.x;
    const int step = blockIdx.x;                // 0..1569
    const float* src = W + (size_t)step * 4096; // 32 k-rows x 128 e, contiguous
    #pragma unroll
    for (int p = 0; p < 16; ++p) {
        int idx = p * 256 + t;
        tile[idx >> 7][idx & 127] = src[idx];
    }
    __syncthreads();
    const int e = t >> 1, half = t & 1;
    short* dst = Wt2 + (size_t)step * 4096 + e * 32 + half * 16;
    #pragma unroll
    for (int q = 0; q < 2; ++q) {
        short8_t pk;
        #pragma unroll
        for (int i = 0; i < 8; ++i) pk[i] = f2bf(tile[half * 16 + q * 8 + i][e]);
        *reinterpret_cast<short8_t*>(dst + q * 8) = pk;
    }
}

// Split-K bf16 MFMA GEMM. This round: memory-level parallelism.
// 4 blocks/CU (grid 1024 = 64 mt x 16 s) and every A-load instruction is one
// row x 1 KB fully contiguous (64 lanes x 4 floats) — copy-bench access shape.
// BK=256 superstep, double-buffered LDS, T14 issue-early/write-late.
__global__ __launch_bounds__(256, 4) void k_main(const float* __restrict__ A,
                                                 const short* __restrict__ Wt2,
                                                 float* __restrict__ P) {
    __shared__ short tile[2][BM][PITCH];        // 33792 B -> 4 blocks/CU

    const int bid = blockIdx.x;
    const int s   = bid & 15;                   // XCD x serves s in {x, x+8}:
    const int mt  = bid >> 4;                   // Wt2 working set ~3.2 MB, L2-resident
    const int t = threadIdx.x, w = t >> 6, l = t & 63;

    const int start  = (s * KSTEPS) / SPLIT;
    const int end    = ((s + 1) * KSTEPS) / SPLIT;
    const int nsteps = end - start;             // 98 or 99
    const int NSS    = (nsteps + BKS - 1) / BKS;
    const size_t kb  = (size_t)start * 32;

    // stage identity: wave w owns rows 8w..8w+7; lane l covers floats 4l..4l+3.
    // One dwordx4 per row per superstep = 1 KB contiguous per instruction.
    const float* arow = A + (size_t)(mt * BM + 8 * w) * VDIM + kb + 4 * l;

    // fragment identity: wave w owns col-fragments {2w, 2w+1}
    const int rl = l & 15, kg = l >> 4;
    const int cf0 = 2 * w;

    char* const lds = (char*)&tile[0][0][0];
    const int fr0 = rl * (PITCH * 2) + kg * 16;     // rowfrag 0 byte offset
    const int fr1 = fr0 + 16 * (PITCH * 2);         // rowfrag 1
    const int swo = (8 * w) * (PITCH * 2) + l * 8;  // stage write byte offset

    float4_t acc[2][2];
    #pragma unroll
    for (int i = 0; i < 2; ++i)
        #pragma unroll
        for (int j = 0; j < 2; ++j) acc[i][j] = (float4_t){0.f, 0.f, 0.f, 0.f};

    float4_t fs[8];                             // 8 rows in flight (32 VGPR)

    // nk = valid k-steps in this superstep; lane participates if its 4 floats
    // fall inside nk*32 (guards the ragged final superstep; no OOB reads).
    auto load_stage = [&](int ssn, int nk) {
        const float* p = arow + (size_t)ssn * (BKS * 32);
        const bool act = (l * 4) < (nk * 32);
        #pragma unroll
        for (int i = 0; i < 8; ++i)
            if (act) __builtin_memcpy(&fs[i], p + (size_t)i * VDIM, 16);
    };
    auto write_stage = [&](int buf, int nk) {
        const bool act = (l * 4) < (nk * 32);
        #pragma unroll
        for (int i = 0; i < 8; ++i)
            if (act) {
                uint2 v;
                v.x = pack_bf2(fs[i][0], fs[i][1]);
                v.y = pack_bf2(fs[i][2], fs[i][3]);
                *reinterpret_cast<uint2*>(lds + buf * LBYTES + swo + i * (PITCH * 2)) = v;
            }
    };
    auto compute_step = [&](int buf, int gstep, int j) {
        const short* bb = Wt2 + (size_t)gstep * 4096 + (size_t)(cf0 * 16 + rl) * 32 + kg * 8;
        short8_t b0 = *reinterpret_cast<const short8_t*>(bb);            // 1 KB coalesced
        short8_t b1 = *reinterpret_cast<const short8_t*>(bb + 16 * 32);  // L2-hot
        short8_t a0 = *reinterpret_cast<const short8_t*>(lds + buf * LBYTES + fr0 + j * 64);
        short8_t a1 = *reinterpret_cast<const short8_t*>(lds + buf * LBYTES + fr1 + j * 64);
        acc[0][0] = __builtin_amdgcn_mfma_f32_16x16x32_bf16(a0, b0, acc[0][0], 0, 0, 0);
        acc[0][1] = __builtin_amdgcn_mfma_f32_16x16x32_bf16(a0, b1, acc[0][1], 0, 0, 0);
        acc[1][0] = __builtin_amdgcn_mfma_f32_16x16x32_bf16(a1, b0, acc[1][0], 0, 0, 0);
        acc[1][1] = __builtin_amdgcn_mfma_f32_16x16x32_bf16(a1, b1, acc[1][1], 0, 0, 0);
    };

    // prologue: stage superstep 0 (nsteps >= 98, so full BKS)
    load_stage(0, BKS);
    write_stage(0, BKS);
    __syncthreads();

    for (int ss = 0; ss < NSS; ++ss) {
        const int buf  = ss & 1;
        const int rem  = nsteps - ss * BKS;
        const int curn = rem < BKS ? rem : BKS;
        const int nrem = nsteps - (ss + 1) * BKS;
        const int nxtn = (ss + 1 < NSS) ? (nrem < BKS ? nrem : BKS) : 0;
        if (nxtn > 0) load_stage(ss + 1, nxtn);   // issue early; outstanding over MFMA
        const int g0 = start + ss * BKS;
        #pragma unroll
        for (int j = 0; j < BKS; ++j)
            if (j < curn) compute_step(buf, g0 + j, j);
        if (nxtn > 0) write_stage(buf ^ 1, nxtn); // vmcnt waits land here
        __syncthreads();
    }

    // Partial write: C/D layout col = lane&15, row = (lane>>4)*4 + j  [m89-verified]
    float* pout = P + ((size_t)s * MROWS + (size_t)mt * BM) * EDIM + cf0 * 16;
    #pragma unroll
    for (int rf = 0; rf < 2; ++rf)
        #pragma unroll
        for (int cf = 0; cf < 2; ++cf)
            #pragma unroll
            for (int j = 0; j < 4; ++j) {
                int rr = rf * 16 + kg * 4 + j;
                int cc = cf * 16 + rl;
                pout[(size_t)rr * EDIM + cc] = acc[rf][cf][j];
            }
}

// out = bias + sum of SPLIT partials + fp32 K-tail, float4-vectorized.
__global__ __launch_bounds__(256) void k_reduce(const float* __restrict__ P,
                                                const float* __restrict__ A,
                                                const float* __restrict__ W,
                                                const float* __restrict__ bias,
                                                float* __restrict__ out) {
    const int i4 = blockIdx.x * 256 + threadIdx.x;   // float4 index, 65536 total
    const int m  = i4 >> 5;                          // 32 float4 per output row
    const int e4 = i4 & 31;
    float4_t acc = reinterpret_cast<const float4_t*>(bias)[e4];
    #pragma unroll
    for (int j = 0; j < KTAIL; ++j) {
        float a = A[(size_t)m * VDIM + KMAIN + j];
        float4_t w = reinterpret_cast<const float4_t*>(W + (size_t)(KMAIN + j) * EDIM)[e4];
        acc += a * w;
    }
    float4_t ps = {0.f, 0.f, 0.f, 0.f};
    #pragma unroll
    for (int p = 0; p < SPLIT; ++p)
        ps += reinterpret_cast<const float4_t*>(P)[(size_t)p * (MROWS * EDIM / 4) + i4];
    acc += ps;
    reinterpret_cast<float4_t*>(out)[i4] = acc;
}

// Emergency fallback if workspace is too small: plain fp32, deterministic.
__global__ __launch_bounds__(256) void k_naive(const float* __restrict__ A,
                                               const float* __restrict__ W,
                                               const float* __restrict__ bias,
                                               float* __restrict__ out) {
    const int e  = threadIdx.x & 127;
    const int mi = threadIdx.x >> 7;
    const int m0 = blockIdx.x * 8 + mi;
    float acc[4] = {0.f, 0.f, 0.f, 0.f};
    for (int k = 0; k < VDIM; ++k) {
        float w = W[(size_t)k * EDIM + e];
        #pragma unroll
        for (int q = 0; q < 4; ++q)
            acc[q] += A[(size_t)(m0 + q * 2) * VDIM + k] * w;
    }
    #pragma unroll
    for (int q = 0; q < 4; ++q)
        out[(size_t)(m0 + q * 2) * EDIM + e] = acc[q] + bias[e];
}

extern "C" void kernel_launch(void* const* d_in, const int* in_sizes, int n_in,
                              void* d_out, int out_size, void* d_ws, size_t ws_size,
                              hipStream_t stream) {
    const float* A    = (const float*)d_in[0];  // (16,128,50257) fp32
    const float* W    = (const float*)d_in[1];  // (50257,128) fp32
    const float* bias = (const float*)d_in[2];  // (128,) fp32
    float* out = (float*)d_out;                 // (16,128,128) fp32

    const size_t WT2_BYTES = (size_t)KSTEPS * 4096 * sizeof(short);         // 12.86 MB
    const size_t P_BYTES   = (size_t)SPLIT * MROWS * EDIM * sizeof(float);  // 16.78 MB

    if (ws_size >= WT2_BYTES + P_BYTES) {
        short* Wt2 = (short*)d_ws;
        float* P   = (float*)((char*)d_ws + WT2_BYTES);
        k_wt2<<<KSTEPS, 256, 0, stream>>>(W, Wt2);
        k_main<<<(MROWS / BM) * SPLIT, 256, 0, stream>>>(A, Wt2, P);
        k_reduce<<<(MROWS * EDIM) / (256 * 4), 256, 0, stream>>>(P, A, W, bias, out);
    } else {
        k_naive<<<MROWS / 8, 256, 0, stream>>>(A, W, bias, out);
    }
}